// Round 12
// baseline (120.331 us; speedup 1.0000x reference)
//
#include <hip/hip_runtime.h>
#include <hip/hip_bf16.h>

// NT-Xent (SimCLR) fused loss, MI355X gfx950. Round 12: OCCUPANCY PUSH.
// Six structures (R3,R7,R8,R9,R10,R11) all plateau at tile ~41-46us with
// 8-11 resident waves/CU and ~85% idle. This round doubles TLP: 512-thr
// blocks, 8 waves of 32x64 wave-tiles, h-serial K-split to keep live regs
// ~115 -> __launch_bounds__(512,4) caps VGPR at 128 -> 4 waves/SIMD =
// 16 waves/CU, 2 resident blocks/CU, 2080 one-tile blocks queued (elastic).
// Zero LDS, zero barriers, fp8 MX MFMA; R3 epilogue (shuffles + atomics,
// both individually proven cost-neutral in R10/R11).
//
// ws layout: [S: N floats][pos: N floats][zn8: N*D fp8 bytes]

#define N_TOT 8192
#define BATCH 4096
#define DIM   256                    // fp8 bytes per row
#define NT_TILES 64                  // 8192 / 128

typedef int   v8i32 __attribute__((ext_vector_type(8)));
typedef float f32x4 __attribute__((ext_vector_type(4)));

// One wave per row: 64 lanes x float4 -> 4 fp8 bytes/lane. Also zeros S.
__global__ __launch_bounds__(256) void normalize_kernel(
    const float* __restrict__ z, unsigned char* __restrict__ zn8,
    float* __restrict__ S) {
  const int wave = threadIdx.x >> 6;
  const int lane = threadIdx.x & 63;
  const int row  = blockIdx.x * 4 + wave;
  float4 v = ((const float4*)(z + (size_t)row * DIM))[lane];
  float ss = v.x * v.x + v.y * v.y + v.z * v.z + v.w * v.w;
#pragma unroll
  for (int m = 1; m <= 32; m <<= 1) ss += __shfl_xor(ss, m);
  float inv = 1.0f / sqrtf(ss);
  int p01 = __builtin_amdgcn_cvt_pk_fp8_f32(v.x * inv, v.y * inv, 0, false);
  int p23 = __builtin_amdgcn_cvt_pk_fp8_f32(v.z * inv, v.w * inv, 0, false);
  unsigned int packed =
      ((unsigned int)p01 & 0xffffu) | ((unsigned int)p23 << 16);
  ((unsigned int*)(zn8 + (size_t)row * DIM))[lane] = packed;
  if (threadIdx.x < 4) S[blockIdx.x * 4 + threadIdx.x] = 0.0f;
}

// 32 contiguous bytes -> one K=128 fp8 MFMA operand fragment (8 VGPRs).
__device__ __forceinline__ v8i32 load_frag_g(const unsigned char* p) {
  int4 lo = *(const int4*)p;
  int4 hi = *(const int4*)(p + 16);
  return (v8i32){lo.x, lo.y, lo.z, lo.w, hi.x, hi.y, hi.z, hi.w};
}

// Upper-triangle 128x128 tiles of sim = zn*zn^T*10, fused exp + row/col
// sums. Grid (33, 64) wrapped: j = blockIdx.x in [0,32], rb_raw =
// blockIdx.y; j==32 only for rb_raw < 32. 512 threads = 8 waves; wave
// (wm,wn) = (wave>>1, wave&1) owns a 32x64 quadrant: 2x4 fragments of
// 16x16x128 MX-fp8 MFMA, K split h-serially (two K=128 passes) to keep
// live registers under the 128-VGPR / 4-waves-per-SIMD budget.
__global__ __launch_bounds__(512, 4) void simclr_tile_kernel(
    const unsigned char* __restrict__ zn8, float* __restrict__ S,
    float* __restrict__ pos) {
  const int j = blockIdx.x, rb_raw = blockIdx.y;
  if (j == 32 && rb_raw >= 32) return;

  const int tid = threadIdx.x;
  const int wave = tid >> 6, lane = tid & 63;
  const int wm = wave >> 1, wn = wave & 1;      // 4 row-groups x 2 col-groups
  const int c = lane & 15, quad = lane >> 4;    // MFMA lane coords

  int cb_raw = rb_raw + j;
  if (cb_raw >= NT_TILES) cb_raw -= NT_TILES;
  const int rb = (cb_raw < rb_raw) ? cb_raw : rb_raw;
  const int cb = (cb_raw < rb_raw) ? rb_raw : cb_raw;
  const bool isdiag = (j == 0);

  f32x4 acc[2][4];
#pragma unroll
  for (int i = 0; i < 2; ++i)
#pragma unroll
    for (int k = 0; k < 4; ++k) acc[i][k] = (f32x4){0.f, 0.f, 0.f, 0.f};

  const unsigned char* aBase =
      zn8 + (size_t)(rb * 128 + wm * 32 + c) * DIM + quad * 32;
  const unsigned char* bBase =
      zn8 + (size_t)(cb * 128 + wn * 64 + c) * DIM + quad * 32;

#pragma unroll
  for (int h = 0; h < 2; ++h) {                 // two K=128 passes
    v8i32 af[2], bf[4];
#pragma unroll
    for (int f = 0; f < 2; ++f)
      af[f] = load_frag_g(aBase + (size_t)f * 16 * DIM + h * 128);
#pragma unroll
    for (int f = 0; f < 4; ++f)
      bf[f] = load_frag_g(bBase + (size_t)f * 16 * DIM + h * 128);
#pragma unroll
    for (int fm = 0; fm < 2; ++fm)
#pragma unroll
      for (int fn = 0; fn < 4; ++fn)
        acc[fm][fn] = __builtin_amdgcn_mfma_scale_f32_16x16x128_f8f6f4(
            af[fm], bf[fn], acc[fm][fn],
            0, 0,                 // cbsz = fp8(A), blgp = fp8(B)
            0, 0x7f,              // opsel_a, scale_a = E8M0 1.0
            0, 0x7f);             // opsel_b, scale_b = E8M0 1.0
  }

  // Epilogue. C/D layout: row = quad*4 + reg, col = lane&15 per 16x16 frag.
  float cs[4] = {0.f, 0.f, 0.f, 0.f};           // per-lane column partials
#pragma unroll
  for (int fm = 0; fm < 2; ++fm) {
#pragma unroll
    for (int r = 0; r < 4; ++r) {
      const int grow = rb * 128 + wm * 32 + fm * 16 + quad * 4 + r;
      float s = 0.f;
#pragma unroll
      for (int fn = 0; fn < 4; ++fn) {
        const int gcol = cb * 128 + wn * 64 + fn * 16 + c;
        const float logit = acc[fm][fn][r] * 10.0f;
        float e = __expf(logit);
        if (isdiag && gcol == grow) e = 0.f;    // exclude self-similarity
        if ((gcol ^ grow) == BATCH) {           // partner pair i <-> i^B
          pos[grow] = logit;                    // unique writer per element
          pos[gcol] = logit;                    // sim symmetric
        }
        s += e;
        cs[fn] += e;
      }
      s += __shfl_xor(s, 1);
      s += __shfl_xor(s, 2);
      s += __shfl_xor(s, 4);
      s += __shfl_xor(s, 8);
      if (c == 0) atomicAdd(&S[grow], s);
    }
  }
  if (!isdiag) {
    // column sums -> S[col]; each of the 4 wm-groups adds its 32-row part.
#pragma unroll
    for (int fn = 0; fn < 4; ++fn) {
      cs[fn] += __shfl_xor(cs[fn], 16);
      cs[fn] += __shfl_xor(cs[fn], 32);
    }
    if (quad == 0) {
#pragma unroll
      for (int fn = 0; fn < 4; ++fn)
        atomicAdd(&S[cb * 128 + wn * 64 + fn * 16 + c], cs[fn]);
    }
  }
}

// loss = mean(log(S_i) - pos_i)
__global__ __launch_bounds__(1024) void finalize_kernel(
    const float* __restrict__ S, const float* __restrict__ pos,
    float* __restrict__ out) {
  const int tid = threadIdx.x;
  float a = 0.f;
  for (int i = tid; i < N_TOT; i += 1024) a += __logf(S[i]) - pos[i];
#pragma unroll
  for (int m = 1; m <= 32; m <<= 1) a += __shfl_xor(a, m);
  __shared__ float red[16];
  if ((tid & 63) == 0) red[tid >> 6] = a;
  __syncthreads();
  if (tid < 16) {
    float v = red[tid];
    v += __shfl_xor(v, 1);
    v += __shfl_xor(v, 2);
    v += __shfl_xor(v, 4);
    v += __shfl_xor(v, 8);
    if (tid == 0) out[0] = v * (1.0f / (float)N_TOT);
  }
}

extern "C" void kernel_launch(void* const* d_in, const int* in_sizes, int n_in,
                              void* d_out, int out_size, void* d_ws,
                              size_t ws_size, hipStream_t stream) {
  const float* z = (const float*)d_in[0];
  float* out = (float*)d_out;
  char* ws = (char*)d_ws;
  float* S = (float*)ws;                                   // N floats
  float* pos = (float*)(ws + N_TOT * sizeof(float));       // N floats
  unsigned char* zn8 =
      (unsigned char*)(ws + 2 * N_TOT * sizeof(float));    // N*D fp8

  normalize_kernel<<<N_TOT / 4, 256, 0, stream>>>(z, zn8, S);
  dim3 grid(33, NT_TILES);
  simclr_tile_kernel<<<grid, 512, 0, stream>>>(zn8, S, pos);
  finalize_kernel<<<1, 1024, 0, stream>>>(S, pos, out);
}

// Round 13
// 99.694 us; speedup vs baseline: 1.2070x; 1.2070x over previous
//
#include <hip/hip_runtime.h>
#include <hip/hip_bf16.h>

// NT-Xent (SimCLR) fused loss, MI355X gfx950. Round 13: HALVE THE LINES.
// Cross-round model: tile time ∝ cache lines through the per-CU VMEM path
// (~10 cyc/64B line): R7 8.3K lines/CU -> 41us, R12 12.6K -> 63us, R1
// 16.6K -> 86us. So: 256x256 fp8 tiles (528 blocks instead of 2080),
// K-split staging (two 128B K-halves, 64KB LDS), 8 waves of 64x128
// wave-tiles, launch_bounds(512,1) to hold ~240 live VGPRs spill-free
// (8 waves/CU, same TLP as R7). Lines/CU: 8.3K -> 4.2K.
//
// ws layout: [S: N floats][pos: N floats][zn8: N*D fp8 bytes]

#define N_TOT 8192
#define BATCH 4096
#define DIM   256                    // fp8 bytes per row
#define TM    256                    // tile edge
#define NTB   32                     // 8192 / 256 bands

typedef int   v8i32 __attribute__((ext_vector_type(8)));
typedef float f32x4 __attribute__((ext_vector_type(4)));

__device__ __forceinline__ void load_lds16(const void* g, void* l) {
  __builtin_amdgcn_global_load_lds(
      (const __attribute__((address_space(1))) unsigned int*)g,
      (__attribute__((address_space(3))) unsigned int*)l,
      16, 0, 0);
}

// One wave per row: 64 lanes x float4 -> 4 fp8 bytes/lane. Also zeros S.
__global__ __launch_bounds__(256) void normalize_kernel(
    const float* __restrict__ z, unsigned char* __restrict__ zn8,
    float* __restrict__ S) {
  const int wave = threadIdx.x >> 6;
  const int lane = threadIdx.x & 63;
  const int row  = blockIdx.x * 4 + wave;
  float4 v = ((const float4*)(z + (size_t)row * DIM))[lane];
  float ss = v.x * v.x + v.y * v.y + v.z * v.z + v.w * v.w;
#pragma unroll
  for (int m = 1; m <= 32; m <<= 1) ss += __shfl_xor(ss, m);
  float inv = 1.0f / sqrtf(ss);
  int p01 = __builtin_amdgcn_cvt_pk_fp8_f32(v.x * inv, v.y * inv, 0, false);
  int p23 = __builtin_amdgcn_cvt_pk_fp8_f32(v.z * inv, v.w * inv, 0, false);
  unsigned int packed =
      ((unsigned int)p01 & 0xffffu) | ((unsigned int)p23 << 16);
  ((unsigned int*)(zn8 + (size_t)row * DIM))[lane] = packed;
  if (threadIdx.x < 4) S[blockIdx.x * 4 + threadIdx.x] = 0.0f;
}

// Upper-triangle 256x256 tiles. Grid (17, 32): j = blockIdx.x in [0,16],
// rb_raw = blockIdx.y; cb_raw = (rb_raw + j) % 32; j==16 only rb_raw < 16.
// 512 threads = 8 waves; wave (wm,wn) = (wave>>1, wave&1) owns 64x128:
// 4x8 fragments of 16x16x128 MX-fp8 MFMA. K staged in two 128B halves.
__global__ __launch_bounds__(512, 1) void simclr_tile_kernel(
    const unsigned char* __restrict__ zn8, float* __restrict__ S,
    float* __restrict__ pos) {
  const int j = blockIdx.x, rb_raw = blockIdx.y;
  if (j == 16 && rb_raw >= 16) return;

  const int tid = threadIdx.x;
  const int wave = tid >> 6, lane = tid & 63;
  const int wm = wave >> 1, wn = wave & 1;      // 4 row-groups x 2 col-groups
  const int c = lane & 15, quad = lane >> 4;    // MFMA lane coords

  int cb_raw = rb_raw + j;
  if (cb_raw >= NTB) cb_raw -= NTB;
  const int rb = (cb_raw < rb_raw) ? cb_raw : rb_raw;
  const int cb = (cb_raw < rb_raw) ? rb_raw : cb_raw;
  const bool isdiag = (j == 0);

  // Per K-half: 256 rows x 128 B each = 32 KB per matrix.
  __shared__ alignas(16) unsigned char As[TM * 128];
  __shared__ alignas(16) unsigned char Bs[TM * 128];

  f32x4 acc[4][8];
#pragma unroll
  for (int i = 0; i < 4; ++i)
#pragma unroll
    for (int k = 0; k < 8; ++k) acc[i][k] = (f32x4){0.f, 0.f, 0.f, 0.f};

  // Staging (per K-half kb): linear id n = i*512 + tid in [0,2048):
  // row = n>>3, LDS chunk s = n&7; fetch global chunk s^(row&7) of the
  // half (XOR swizzle -> fragment ds_read_b128 conflict-free, measured 0).
  // Within a wave LDS addresses are base + lane*16 (global_load_lds rule).
  const size_t a_row0 = (size_t)rb * TM;
  const size_t b_row0 = (size_t)cb * TM;

#pragma unroll
  for (int kb = 0; kb < 2; ++kb) {
#pragma unroll
    for (int i = 0; i < 4; ++i) {
      const int n = i * 512 + tid;
      const int row = n >> 3, s = n & 7;
      const int gch = s ^ (row & 7);
      load_lds16(zn8 + (a_row0 + row) * DIM + kb * 128 + gch * 16,
                 As + row * 128 + s * 16);
      load_lds16(zn8 + (b_row0 + row) * DIM + kb * 128 + gch * 16,
                 Bs + row * 128 + s * 16);
    }
    __syncthreads();

    // Fragments: lane (c,quad) needs global chunks 2q, 2q+1 of its row ->
    // LDS chunks (2q)^(c&7) and ((2q)^(c&7))^1 (row&7 == c&7 here).
    const int c0 = (2 * quad) ^ (c & 7);
    v8i32 af[4], bf[8];
#pragma unroll
    for (int f = 0; f < 4; ++f) {
      const int4* Ar = (const int4*)(As + (size_t)(wm * 64 + f * 16 + c) * 128);
      int4 lo = Ar[c0], hi = Ar[c0 ^ 1];
      af[f] = (v8i32){lo.x, lo.y, lo.z, lo.w, hi.x, hi.y, hi.z, hi.w};
    }
#pragma unroll
    for (int f = 0; f < 8; ++f) {
      const int4* Br = (const int4*)(Bs + (size_t)(wn * 128 + f * 16 + c) * 128);
      int4 lo = Br[c0], hi = Br[c0 ^ 1];
      bf[f] = (v8i32){lo.x, lo.y, lo.z, lo.w, hi.x, hi.y, hi.z, hi.w};
    }
#pragma unroll
    for (int fm = 0; fm < 4; ++fm)
#pragma unroll
      for (int fn = 0; fn < 8; ++fn)
        acc[fm][fn] = __builtin_amdgcn_mfma_scale_f32_16x16x128_f8f6f4(
            af[fm], bf[fn], acc[fm][fn],
            0, 0,                 // cbsz = fp8(A), blgp = fp8(B)
            0, 0x7f,              // opsel_a, scale_a = E8M0 1.0
            0, 0x7f);             // opsel_b, scale_b = E8M0 1.0
    __syncthreads();
  }

  // Epilogue. C/D layout: row = quad*4 + reg, col = lane&15 per 16x16 frag.
  float cs[8] = {0.f, 0.f, 0.f, 0.f, 0.f, 0.f, 0.f, 0.f};
#pragma unroll
  for (int fm = 0; fm < 4; ++fm) {
#pragma unroll
    for (int r = 0; r < 4; ++r) {
      const int grow = rb * TM + wm * 64 + fm * 16 + quad * 4 + r;
      float s = 0.f;
#pragma unroll
      for (int fn = 0; fn < 8; ++fn) {
        const int gcol = cb * TM + wn * 128 + fn * 16 + c;
        const float logit = acc[fm][fn][r] * 10.0f;
        float e = __expf(logit);
        if (isdiag && gcol == grow) e = 0.f;    // exclude self-similarity
        if ((gcol ^ grow) == BATCH) {           // partner pair i <-> i^B
          pos[grow] = logit;                    // unique writer per element
          pos[gcol] = logit;                    // sim symmetric
        }
        s += e;
        cs[fn] += e;
      }
      s += __shfl_xor(s, 1);
      s += __shfl_xor(s, 2);
      s += __shfl_xor(s, 4);
      s += __shfl_xor(s, 8);
      if (c == 0) atomicAdd(&S[grow], s);
    }
  }
  if (!isdiag) {
    // column sums -> S[col]; each wm-group adds its 64-row slice.
#pragma unroll
    for (int fn = 0; fn < 8; ++fn) {
      cs[fn] += __shfl_xor(cs[fn], 16);
      cs[fn] += __shfl_xor(cs[fn], 32);
    }
    if (quad == 0) {
#pragma unroll
      for (int fn = 0; fn < 8; ++fn)
        atomicAdd(&S[cb * TM + wn * 128 + fn * 16 + c], cs[fn]);
    }
  }
}

// loss = mean(log(S_i) - pos_i)
__global__ __launch_bounds__(1024) void finalize_kernel(
    const float* __restrict__ S, const float* __restrict__ pos,
    float* __restrict__ out) {
  const int tid = threadIdx.x;
  float a = 0.f;
  for (int i = tid; i < N_TOT; i += 1024) a += __logf(S[i]) - pos[i];
#pragma unroll
  for (int m = 1; m <= 32; m <<= 1) a += __shfl_xor(a, m);
  __shared__ float red[16];
  if ((tid & 63) == 0) red[tid >> 6] = a;
  __syncthreads();
  if (tid < 16) {
    float v = red[tid];
    v += __shfl_xor(v, 1);
    v += __shfl_xor(v, 2);
    v += __shfl_xor(v, 4);
    v += __shfl_xor(v, 8);
    if (tid == 0) out[0] = v * (1.0f / (float)N_TOT);
  }
}

extern "C" void kernel_launch(void* const* d_in, const int* in_sizes, int n_in,
                              void* d_out, int out_size, void* d_ws,
                              size_t ws_size, hipStream_t stream) {
  const float* z = (const float*)d_in[0];
  float* out = (float*)d_out;
  char* ws = (char*)d_ws;
  float* S = (float*)ws;                                   // N floats
  float* pos = (float*)(ws + N_TOT * sizeof(float));       // N floats
  unsigned char* zn8 =
      (unsigned char*)(ws + 2 * N_TOT * sizeof(float));    // N*D fp8

  normalize_kernel<<<N_TOT / 4, 256, 0, stream>>>(z, zn8, S);
  dim3 grid(17, NTB);
  simclr_tile_kernel<<<grid, 512, 0, stream>>>(zn8, S, pos);
  finalize_kernel<<<1, 1024, 0, stream>>>(S, pos, out);
}